// Round 7
// baseline (1905.912 us; speedup 1.0000x reference)
//
#include <hip/hip_runtime.h>

// Liquid-network scan: one block per batch row (B=128 blocks), 256 threads.
// r7: NO s_barrier in the scan loop. The 4 co-resident waves sync via a
// monotonic LDS flag handshake (flags[kq] = t+1 after the partial write;
// spin-poll the other three). Structure otherwise = r6: h lives in packed
// fp16 registers (pkX/pkY), broadcast via v_readlane; 4-way k-split dot
// (32 readlane + 128 dot2 per wave); double-buffered partial exchange;
// ALL waves redundantly run combine + DPP reduce + LN + tanh + update.
// Tail strength-reduced: gi/bbi pre-scaled by 2*log2(e) so tanh uses
// v_exp_f32 directly; Euler update folded to h*dec + fma(-2DT, rcp, DT).

#define BB     128
#define TT     2048
#define DIN    16
#define HH     256
#define NAPP   10
#define NT     256
#define DT_STEP 0.1f
#define LN_EPS_C 1e-5f
#define LOG2E2  2.8853900817779268f   // 2*log2(e)

typedef _Float16 half2_t __attribute__((ext_vector_type(2)));

template<int CTRL>
__device__ __forceinline__ float dpp_mov0(float x) {
    return __builtin_bit_cast(float,
        __builtin_amdgcn_update_dpp(0, __builtin_bit_cast(int, x), CTRL, 0xF, 0xF, true));
}

// After this, lane 63 holds the wave-wide sums of s1 and s2. (HW-verified r3-r6.)
__device__ __forceinline__ void wave_reduce2(float& s1, float& s2) {
    s1 += dpp_mov0<0x111>(s1); s2 += dpp_mov0<0x111>(s2);  // row_shr:1
    s1 += dpp_mov0<0x112>(s1); s2 += dpp_mov0<0x112>(s2);  // row_shr:2
    s1 += dpp_mov0<0x114>(s1); s2 += dpp_mov0<0x114>(s2);  // row_shr:4
    s1 += dpp_mov0<0x118>(s1); s2 += dpp_mov0<0x118>(s2);  // row_shr:8
    s1 += dpp_mov0<0x142>(s1); s2 += dpp_mov0<0x142>(s2);  // row_bcast:15
    s1 += dpp_mov0<0x143>(s1); s2 += dpp_mov0<0x143>(s2);  // row_bcast:31
}

__device__ __forceinline__ half2_t as_h2(int v) { return __builtin_bit_cast(half2_t, v); }
__device__ __forceinline__ float rl63(float v) {
    return __builtin_bit_cast(float,
        __builtin_amdgcn_readlane(__builtin_bit_cast(int, v), 63));
}
__device__ __forceinline__ float softplus_f(float v) {
    return (v > 20.f) ? v : log1pf(__expf(v));
}
__device__ __forceinline__ float exp2_fast(float v) {
    float r;
    asm("v_exp_f32 %0, %1" : "=v"(r) : "v"(v));   // D = 2^S0
    return r;
}

__global__ __launch_bounds__(NT, 1)
void liquid_scan_kernel(const float* __restrict__ x,
                        const float* __restrict__ W_in,
                        const float* __restrict__ b_in,
                        const float* __restrict__ tau_param,
                        const float* __restrict__ W_rec,
                        const float* __restrict__ g_intra,
                        const float* __restrict__ b_intra,
                        const float* __restrict__ g_norm,
                        const float* __restrict__ b_norm,
                        const float* __restrict__ W_head,
                        const float* __restrict__ b_head,
                        float* __restrict__ out)
{
    const int tid  = threadIdx.x;
    const int b    = blockIdx.x;
    const int lane = tid & 63;
    const int kq   = tid >> 6;          // wave id == k-quarter (wave-uniform)
    const int j0   = lane * 4;          // this lane's 4 output columns

    __shared__ __align__(16) float    x_lds[TT * DIN];   // 128 KB
    __shared__ __align__(16) float    part[2][4][HH];    // 8 KB, double-buffered
    __shared__ __align__(16) unsigned flags[4];          // monotonic step counters

    // ---- stage the whole x[b] into LDS (coalesced float4; once) ----
    {
        const float4* xg = (const float4*)(x + (size_t)b * TT * DIN);
        float4* xl = (float4*)x_lds;
        #pragma unroll 4
        for (int i = tid; i < TT * DIN / 4; i += NT) xl[i] = xg[i];
    }
    if (tid < 4) flags[tid] = 0u;

    // ---- packed recurrent weights: w2[c][p] = (W[64kq+2p][j0+c], W[64kq+2p+1][j0+c])
    half2_t w2[4][32];
    #pragma unroll
    for (int p = 0; p < 32; ++p) {
        const float* r0 = W_rec + (size_t)(64 * kq + 2 * p) * HH + j0;
        const float* r1 = r0 + HH;
        #pragma unroll
        for (int c = 0; c < 4; ++c) {
            half2_t t2; t2.x = (_Float16)r0[c]; t2.y = (_Float16)r1[c];
            w2[c][p] = t2;
        }
    }

    // input-proj weights: this wave covers input dims [4kq, 4kq+4)
    float win[4][4];
    #pragma unroll
    for (int c = 0; c < 4; ++c) {
        #pragma unroll
        for (int r = 0; r < 4; ++r)
            win[c][r] = W_in[(size_t)(j0 + c) * DIN + 4 * kq + r];
    }

    // ---- per-lane params (all waves; tail is redundant) ----
    float bi_[4], gi2_[4], bbi2_[4], dec_[4], gn_[4], bn_[4];
    {
        const float4 v0 = *(const float4*)(b_in      + j0);
        const float4 v1 = *(const float4*)(g_intra   + j0);
        const float4 v2 = *(const float4*)(b_intra   + j0);
        const float4 v3 = *(const float4*)(tau_param + j0);
        const float4 v4 = *(const float4*)(g_norm    + j0);
        const float4 v5 = *(const float4*)(b_norm    + j0);
        bi_[0] = v0.x; bi_[1] = v0.y; bi_[2] = v0.z; bi_[3] = v0.w;
        gi2_[0] = v1.x * LOG2E2; gi2_[1] = v1.y * LOG2E2;
        gi2_[2] = v1.z * LOG2E2; gi2_[3] = v1.w * LOG2E2;
        bbi2_[0] = v2.x * LOG2E2; bbi2_[1] = v2.y * LOG2E2;
        bbi2_[2] = v2.z * LOG2E2; bbi2_[3] = v2.w * LOG2E2;
        dec_[0] = 1.f - DT_STEP / softplus_f(v3.x);
        dec_[1] = 1.f - DT_STEP / softplus_f(v3.y);
        dec_[2] = 1.f - DT_STEP / softplus_f(v3.z);
        dec_[3] = 1.f - DT_STEP / softplus_f(v3.w);
        gn_[0] = v4.x; gn_[1] = v4.y; gn_[2] = v4.z; gn_[3] = v4.w;
        bn_[0] = v5.x; bn_[1] = v5.y; bn_[2] = v5.z; bn_[3] = v5.w;
    }

    float hj[4] = {0.f, 0.f, 0.f, 0.f};
    int pkX = 0, pkY = 0;   // packed fp16 pairs (h[4l],h[4l+1]) and (h[4l+2],h[4l+3])
    const int rlbase = 16 * kq;          // wave-uniform readlane base
    const int o1 = (kq + 1) & 3, o2 = (kq + 2) & 3, o3 = (kq + 3) & 3;
    volatile unsigned* vfl = (volatile unsigned*)flags;

    __syncthreads();   // once: x staged, flags zeroed

    #pragma unroll 1
    for (int t = 0; t < TT; ++t) {
        // broadcast x slice for this wave's 4 input dims (same addr all lanes)
        const float4 xs = *(const float4*)&x_lds[t * DIN + 4 * kq];

        // ---- dot: 32 readlane from REGISTERS, each feeding 4 dot2
        float a0 = 0.f, a1 = 0.f, a2 = 0.f, a3 = 0.f;
        #pragma unroll
        for (int p = 0; p < 32; ++p) {
            const int r = __builtin_amdgcn_readlane((p & 1) ? pkY : pkX,
                                                    rlbase + (p >> 1));
            a0 = __builtin_amdgcn_fdot2(as_h2(r), w2[0][p], a0, false);
            a1 = __builtin_amdgcn_fdot2(as_h2(r), w2[1][p], a1, false);
            a2 = __builtin_amdgcn_fdot2(as_h2(r), w2[2][p], a2, false);
            a3 = __builtin_amdgcn_fdot2(as_h2(r), w2[3][p], a3, false);
        }
        // ---- input projection for this wave's 4 input dims
        a0 = fmaf(xs.x, win[0][0], a0); a0 = fmaf(xs.y, win[0][1], a0);
        a0 = fmaf(xs.z, win[0][2], a0); a0 = fmaf(xs.w, win[0][3], a0);
        a1 = fmaf(xs.x, win[1][0], a1); a1 = fmaf(xs.y, win[1][1], a1);
        a1 = fmaf(xs.z, win[1][2], a1); a1 = fmaf(xs.w, win[1][3], a1);
        a2 = fmaf(xs.x, win[2][0], a2); a2 = fmaf(xs.y, win[2][1], a2);
        a2 = fmaf(xs.z, win[2][2], a2); a2 = fmaf(xs.w, win[2][3], a2);
        a3 = fmaf(xs.x, win[3][0], a3); a3 = fmaf(xs.y, win[3][1], a3);
        a3 = fmaf(xs.z, win[3][2], a3); a3 = fmaf(xs.w, win[3][3], a3);

        // ---- flag handshake replaces s_barrier ----
        const unsigned tgt = (unsigned)(t + 1);
        ((float4*)part[t & 1][kq])[lane] = make_float4(a0, a1, a2, a3);
        asm volatile("s_waitcnt lgkmcnt(0)" ::: "memory");  // partial visible first
        if (lane == 0) vfl[kq] = tgt;
        unsigned f1, f2, f3;
        do {
            f1 = vfl[o1]; f2 = vfl[o2]; f3 = vfl[o3];
        } while (f1 < tgt || f2 < tgt || f3 < tgt);
        asm volatile("" ::: "memory");   // no LDS reads hoisted above the poll

        const float4 p1 = ((const float4*)part[t & 1][o1])[lane];
        const float4 p2 = ((const float4*)part[t & 1][o2])[lane];
        const float4 p3 = ((const float4*)part[t & 1][o3])[lane];
        float u[4];
        u[0] = (a0 + p1.x) + (p2.x + p3.x) + bi_[0];
        u[1] = (a1 + p1.y) + (p2.y + p3.y) + bi_[1];
        u[2] = (a2 + p1.z) + (p2.z + p3.z) + bi_[2];
        u[3] = (a3 + p1.w) + (p2.w + p3.w) + bi_[3];

        float s1 = (u[0] + u[1]) + (u[2] + u[3]);
        float s2 = (u[0] * u[0] + u[1] * u[1]) + (u[2] * u[2] + u[3] * u[3]);
        wave_reduce2(s1, s2);
        const float S1 = rl63(s1);
        const float S2 = rl63(s2);
        const float mu  = S1 * (1.f / HH);
        const float var = S2 * (1.f / HH) - mu * mu;
        const float rs  = __builtin_amdgcn_rsqf(var + LN_EPS_C);
        #pragma unroll
        for (int c = 0; c < 4; ++c) {
            // tanh(xn) with 2*log2e pre-folded: e = 2^((u-mu)*rs*gi2 + bbi2)
            const float xn2 = fmaf((u[c] - mu) * rs, gi2_[c], bbi2_[c]);
            const float e   = exp2_fast(xn2);
            const float r   = __builtin_amdgcn_rcpf(e + 1.f);   // rcp(inf)=0, rcp(1)=1
            // h' = clamp(h*dec + DT*(1-2r)) ; DT*(1-2r) = fma(-2DT, r, DT)
            const float fdt = fmaf(-2.f * DT_STEP, r, DT_STEP);
            float v = fmaf(hj[c], dec_[c], fdt);
            v = fminf(10.f, fmaxf(-10.f, v));
            hj[c] = v;
        }
        pkX = __builtin_bit_cast(int, __builtin_amdgcn_cvt_pkrtz(hj[0], hj[1]));
        pkY = __builtin_bit_cast(int, __builtin_amdgcn_cvt_pkrtz(hj[2], hj[3]));
    }

    // ---- final LayerNorm (g_norm, b_norm) + head (wave 0 only) ----
    if (kq == 0) {
        float s1 = (hj[0] + hj[1]) + (hj[2] + hj[3]);
        float s2 = (hj[0] * hj[0] + hj[1] * hj[1]) + (hj[2] * hj[2] + hj[3] * hj[3]);
        wave_reduce2(s1, s2);
        const float S1 = rl63(s1);
        const float S2 = rl63(s2);
        const float mu  = S1 * (1.f / HH);
        const float var = S2 * (1.f / HH) - mu * mu;
        const float rs  = rsqrtf(var + LN_EPS_C);
        float4 ho;
        ho.x = (hj[0] - mu) * rs * gn_[0] + bn_[0];
        ho.y = (hj[1] - mu) * rs * gn_[1] + bn_[1];
        ho.z = (hj[2] - mu) * rs * gn_[2] + bn_[2];
        ho.w = (hj[3] - mu) * rs * gn_[3] + bn_[3];
        ((float4*)part[0][0])[lane] = ho;
    }
    __syncthreads();
    if (tid < NAPP) {
        float o = b_head[tid];
        for (int jj = 0; jj < HH; ++jj)
            o = fmaf(part[0][0][jj], W_head[jj * NAPP + tid], o);
        out[(size_t)b * NAPP + tid] = o;
    }
}

extern "C" void kernel_launch(void* const* d_in, const int* in_sizes, int n_in,
                              void* d_out, int out_size, void* d_ws, size_t ws_size,
                              hipStream_t stream) {
    const float* x       = (const float*)d_in[0];
    const float* W_in    = (const float*)d_in[1];
    const float* b_in    = (const float*)d_in[2];
    const float* tau     = (const float*)d_in[3];
    const float* W_rec   = (const float*)d_in[4];
    const float* g_intra = (const float*)d_in[5];
    const float* b_intra = (const float*)d_in[6];
    const float* g_norm  = (const float*)d_in[7];
    const float* b_norm  = (const float*)d_in[8];
    const float* W_head  = (const float*)d_in[9];
    const float* b_head  = (const float*)d_in[10];
    float* out = (float*)d_out;

    hipLaunchKernelGGL(liquid_scan_kernel, dim3(BB), dim3(NT), 0, stream,
                       x, W_in, b_in, tau, W_rec, g_intra, b_intra,
                       g_norm, b_norm, W_head, b_head, out);
}

// Round 8
// 1576.393 us; speedup vs baseline: 1.2090x; 1.2090x over previous
//
#include <hip/hip_runtime.h>

// Liquid-network scan: one block per batch row (B=128 blocks), 256 threads.
// r8 = r6 skeleton (register-resident packed-fp16 h, readlane broadcast,
// 4-way k-split, double-buffered partial exchange, ONE s_barrier/step,
// redundant LN tail on all 4 waves) with the dot rebuilt around SIXTEEN
// independent accumulator chains (4 per output column) in 8 groups of
// {4 readlane -> 16 fdot2}. Same-chain reuse distance ~40 issue cycles,
// so fdot2 dependent latency (the suspected ~1000-cyc/step stall common
// to r3-r7's 32-deep chains) is fully hidden.

#define BB     128
#define TT     2048
#define DIN    16
#define HH     256
#define NAPP   10
#define NT     256
#define DT_STEP 0.1f
#define LN_EPS_C 1e-5f
#define LOG2E2  2.8853900817779268f   // 2*log2(e)

typedef _Float16 half2_t __attribute__((ext_vector_type(2)));

template<int CTRL>
__device__ __forceinline__ float dpp_mov0(float x) {
    return __builtin_bit_cast(float,
        __builtin_amdgcn_update_dpp(0, __builtin_bit_cast(int, x), CTRL, 0xF, 0xF, true));
}

// After this, lane 63 holds the wave-wide sums of s1 and s2. (HW-verified r3-r7.)
__device__ __forceinline__ void wave_reduce2(float& s1, float& s2) {
    s1 += dpp_mov0<0x111>(s1); s2 += dpp_mov0<0x111>(s2);  // row_shr:1
    s1 += dpp_mov0<0x112>(s1); s2 += dpp_mov0<0x112>(s2);  // row_shr:2
    s1 += dpp_mov0<0x114>(s1); s2 += dpp_mov0<0x114>(s2);  // row_shr:4
    s1 += dpp_mov0<0x118>(s1); s2 += dpp_mov0<0x118>(s2);  // row_shr:8
    s1 += dpp_mov0<0x142>(s1); s2 += dpp_mov0<0x142>(s2);  // row_bcast:15
    s1 += dpp_mov0<0x143>(s1); s2 += dpp_mov0<0x143>(s2);  // row_bcast:31
}

__device__ __forceinline__ half2_t as_h2(int v) { return __builtin_bit_cast(half2_t, v); }
__device__ __forceinline__ float rl63(float v) {
    return __builtin_bit_cast(float,
        __builtin_amdgcn_readlane(__builtin_bit_cast(int, v), 63));
}
__device__ __forceinline__ float softplus_f(float v) {
    return (v > 20.f) ? v : log1pf(__expf(v));
}
__device__ __forceinline__ float exp2_fast(float v) {
    float r;
    asm("v_exp_f32 %0, %1" : "=v"(r) : "v"(v));   // D = 2^S0
    return r;
}

__global__ __launch_bounds__(NT, 1)
void liquid_scan_kernel(const float* __restrict__ x,
                        const float* __restrict__ W_in,
                        const float* __restrict__ b_in,
                        const float* __restrict__ tau_param,
                        const float* __restrict__ W_rec,
                        const float* __restrict__ g_intra,
                        const float* __restrict__ b_intra,
                        const float* __restrict__ g_norm,
                        const float* __restrict__ b_norm,
                        const float* __restrict__ W_head,
                        const float* __restrict__ b_head,
                        float* __restrict__ out)
{
    const int tid  = threadIdx.x;
    const int b    = blockIdx.x;
    const int lane = tid & 63;
    const int kq   = tid >> 6;          // wave id == k-quarter (wave-uniform)
    const int j0   = lane * 4;          // this lane's 4 output columns

    __shared__ __align__(16) float x_lds[TT * DIN];     // 128 KB
    __shared__ __align__(16) float part[2][4][HH];      // 8 KB, double-buffered

    // ---- stage the whole x[b] into LDS (coalesced float4; once) ----
    {
        const float4* xg = (const float4*)(x + (size_t)b * TT * DIN);
        float4* xl = (float4*)x_lds;
        #pragma unroll 4
        for (int i = tid; i < TT * DIN / 4; i += NT) xl[i] = xg[i];
    }

    // ---- packed recurrent weights: w2[c][p] = (W[64kq+2p][j0+c], W[64kq+2p+1][j0+c])
    half2_t w2[4][32];
    #pragma unroll
    for (int p = 0; p < 32; ++p) {
        const float* r0 = W_rec + (size_t)(64 * kq + 2 * p) * HH + j0;
        const float* r1 = r0 + HH;
        #pragma unroll
        for (int c = 0; c < 4; ++c) {
            half2_t t2; t2.x = (_Float16)r0[c]; t2.y = (_Float16)r1[c];
            w2[c][p] = t2;
        }
    }

    // input-proj weights: this wave covers input dims [4kq, 4kq+4)
    float win[4][4];
    #pragma unroll
    for (int c = 0; c < 4; ++c) {
        #pragma unroll
        for (int r = 0; r < 4; ++r)
            win[c][r] = W_in[(size_t)(j0 + c) * DIN + 4 * kq + r];
    }

    // ---- per-lane params (all waves; tail is redundant) ----
    float bi_[4], gi2_[4], bbi2_[4], dec_[4], gn_[4], bn_[4];
    {
        const float4 v0 = *(const float4*)(b_in      + j0);
        const float4 v1 = *(const float4*)(g_intra   + j0);
        const float4 v2 = *(const float4*)(b_intra   + j0);
        const float4 v3 = *(const float4*)(tau_param + j0);
        const float4 v4 = *(const float4*)(g_norm    + j0);
        const float4 v5 = *(const float4*)(b_norm    + j0);
        bi_[0] = v0.x; bi_[1] = v0.y; bi_[2] = v0.z; bi_[3] = v0.w;
        gi2_[0] = v1.x * LOG2E2; gi2_[1] = v1.y * LOG2E2;
        gi2_[2] = v1.z * LOG2E2; gi2_[3] = v1.w * LOG2E2;
        bbi2_[0] = v2.x * LOG2E2; bbi2_[1] = v2.y * LOG2E2;
        bbi2_[2] = v2.z * LOG2E2; bbi2_[3] = v2.w * LOG2E2;
        dec_[0] = 1.f - DT_STEP / softplus_f(v3.x);
        dec_[1] = 1.f - DT_STEP / softplus_f(v3.y);
        dec_[2] = 1.f - DT_STEP / softplus_f(v3.z);
        dec_[3] = 1.f - DT_STEP / softplus_f(v3.w);
        gn_[0] = v4.x; gn_[1] = v4.y; gn_[2] = v4.z; gn_[3] = v4.w;
        bn_[0] = v5.x; bn_[1] = v5.y; bn_[2] = v5.z; bn_[3] = v5.w;
    }

    float hj[4] = {0.f, 0.f, 0.f, 0.f};
    int pkX = 0, pkY = 0;   // packed fp16 pairs (h[4l],h[4l+1]) and (h[4l+2],h[4l+3])
    const int rlbase = 16 * kq;          // wave-uniform readlane base
    const int o1 = (kq + 1) & 3, o2 = (kq + 2) & 3, o3 = (kq + 3) & 3;

    __syncthreads();   // x staged

    #pragma unroll 1
    for (int t = 0; t < TT; ++t) {
        // broadcast x slice for this wave's 4 input dims (same addr all lanes)
        const float4 xs = *(const float4*)&x_lds[t * DIN + 4 * kq];

        // ---- dot: 8 groups of {4 readlane -> 16 fdot2}; 16 indep. acc chains
        float acc[4][4];
        #pragma unroll
        for (int c = 0; c < 4; ++c) {
            #pragma unroll
            for (int i = 0; i < 4; ++i) acc[c][i] = 0.f;
        }
        #pragma unroll
        for (int g = 0; g < 8; ++g) {
            const int r0 = __builtin_amdgcn_readlane(pkX, rlbase + 2 * g);
            const int r1 = __builtin_amdgcn_readlane(pkY, rlbase + 2 * g);
            const int r2 = __builtin_amdgcn_readlane(pkX, rlbase + 2 * g + 1);
            const int r3 = __builtin_amdgcn_readlane(pkY, rlbase + 2 * g + 1);
            #pragma unroll
            for (int c = 0; c < 4; ++c)
                acc[c][0] = __builtin_amdgcn_fdot2(as_h2(r0), w2[c][4 * g + 0], acc[c][0], false);
            #pragma unroll
            for (int c = 0; c < 4; ++c)
                acc[c][1] = __builtin_amdgcn_fdot2(as_h2(r1), w2[c][4 * g + 1], acc[c][1], false);
            #pragma unroll
            for (int c = 0; c < 4; ++c)
                acc[c][2] = __builtin_amdgcn_fdot2(as_h2(r2), w2[c][4 * g + 2], acc[c][2], false);
            #pragma unroll
            for (int c = 0; c < 4; ++c)
                acc[c][3] = __builtin_amdgcn_fdot2(as_h2(r3), w2[c][4 * g + 3], acc[c][3], false);
        }
        // ---- input projection: one fma per (column, chain)
        const float xsv[4] = {xs.x, xs.y, xs.z, xs.w};
        #pragma unroll
        for (int c = 0; c < 4; ++c) {
            #pragma unroll
            for (int i = 0; i < 4; ++i)
                acc[c][i] = fmaf(xsv[i], win[c][i], acc[c][i]);
        }
        float a[4];
        #pragma unroll
        for (int c = 0; c < 4; ++c)
            a[c] = (acc[c][0] + acc[c][1]) + (acc[c][2] + acc[c][3]);

        ((float4*)part[t & 1][kq])[lane] = make_float4(a[0], a[1], a[2], a[3]);
        __syncthreads();   // the ONLY barrier per step

        const float4 p1 = ((const float4*)part[t & 1][o1])[lane];
        const float4 p2 = ((const float4*)part[t & 1][o2])[lane];
        const float4 p3 = ((const float4*)part[t & 1][o3])[lane];
        float u[4];
        u[0] = (a[0] + p1.x) + (p2.x + p3.x) + bi_[0];
        u[1] = (a[1] + p1.y) + (p2.y + p3.y) + bi_[1];
        u[2] = (a[2] + p1.z) + (p2.z + p3.z) + bi_[2];
        u[3] = (a[3] + p1.w) + (p2.w + p3.w) + bi_[3];

        float s1 = (u[0] + u[1]) + (u[2] + u[3]);
        float s2 = (u[0] * u[0] + u[1] * u[1]) + (u[2] * u[2] + u[3] * u[3]);
        wave_reduce2(s1, s2);
        const float S1 = rl63(s1);
        const float S2 = rl63(s2);
        const float mu  = S1 * (1.f / HH);
        const float var = S2 * (1.f / HH) - mu * mu;
        const float rs  = __builtin_amdgcn_rsqf(var + LN_EPS_C);
        #pragma unroll
        for (int c = 0; c < 4; ++c) {
            // tanh(xn) with 2*log2e pre-folded: e = 2^((u-mu)*rs*gi2 + bbi2)
            const float xn2 = fmaf((u[c] - mu) * rs, gi2_[c], bbi2_[c]);
            const float e   = exp2_fast(xn2);
            const float r   = __builtin_amdgcn_rcpf(e + 1.f);   // rcp(inf)=0, rcp(1)=1
            const float fdt = fmaf(-2.f * DT_STEP, r, DT_STEP);
            const float v   = fmaf(hj[c], dec_[c], fdt);
            hj[c] = __builtin_amdgcn_fmed3f(v, -10.f, 10.f);
        }
        pkX = __builtin_bit_cast(int, __builtin_amdgcn_cvt_pkrtz(hj[0], hj[1]));
        pkY = __builtin_bit_cast(int, __builtin_amdgcn_cvt_pkrtz(hj[2], hj[3]));
    }

    // ---- final LayerNorm (g_norm, b_norm) + head (wave 0 only) ----
    if (kq == 0) {
        float s1 = (hj[0] + hj[1]) + (hj[2] + hj[3]);
        float s2 = (hj[0] * hj[0] + hj[1] * hj[1]) + (hj[2] * hj[2] + hj[3] * hj[3]);
        wave_reduce2(s1, s2);
        const float S1 = rl63(s1);
        const float S2 = rl63(s2);
        const float mu  = S1 * (1.f / HH);
        const float var = S2 * (1.f / HH) - mu * mu;
        const float rs  = rsqrtf(var + LN_EPS_C);
        float4 ho;
        ho.x = (hj[0] - mu) * rs * gn_[0] + bn_[0];
        ho.y = (hj[1] - mu) * rs * gn_[1] + bn_[1];
        ho.z = (hj[2] - mu) * rs * gn_[2] + bn_[2];
        ho.w = (hj[3] - mu) * rs * gn_[3] + bn_[3];
        ((float4*)part[0][0])[lane] = ho;
    }
    __syncthreads();
    if (tid < NAPP) {
        float o = b_head[tid];
        for (int jj = 0; jj < HH; ++jj)
            o = fmaf(part[0][0][jj], W_head[jj * NAPP + tid], o);
        out[(size_t)b * NAPP + tid] = o;
    }
}

extern "C" void kernel_launch(void* const* d_in, const int* in_sizes, int n_in,
                              void* d_out, int out_size, void* d_ws, size_t ws_size,
                              hipStream_t stream) {
    const float* x       = (const float*)d_in[0];
    const float* W_in    = (const float*)d_in[1];
    const float* b_in    = (const float*)d_in[2];
    const float* tau     = (const float*)d_in[3];
    const float* W_rec   = (const float*)d_in[4];
    const float* g_intra = (const float*)d_in[5];
    const float* b_intra = (const float*)d_in[6];
    const float* g_norm  = (const float*)d_in[7];
    const float* b_norm  = (const float*)d_in[8];
    const float* W_head  = (const float*)d_in[9];
    const float* b_head  = (const float*)d_in[10];
    float* out = (float*)d_out;

    hipLaunchKernelGGL(liquid_scan_kernel, dim3(BB), dim3(NT), 0, stream,
                       x, W_in, b_in, tau, W_rec, g_intra, b_intra,
                       g_norm, b_norm, W_head, b_head, out);
}